// Round 10
// baseline (356.373 us; speedup 1.0000x reference)
//
#include <hip/hip_runtime.h>

#define B_ 8
#define Q_ 64
#define K_ 512
#define NU_ 512
#define D_ 512

typedef __attribute__((ext_vector_type(8))) _Float16 half8;
typedef __attribute__((ext_vector_type(4))) _Float16 half4;
typedef __attribute__((ext_vector_type(16))) float floatx16;

#define C2F 2.8853900817779268f  // 2*log2(e)

// ws float-layout
#define WS_V 0                   // v[0..511], vtot at [512]
#define WS_EQ 640                // Eq: 8*64*512
#define WS_EK (640 + 262144)     // Ek: 8*512*512
#define WS_S (WS_EK + 2097152)   // S raw scores: 8*64*512
#define WS_FLOATS (WS_S + 262144)
#define AH_ELEMS 2359296         // 8 b * 576 rows (512 keys + 64 query) * 512
#define WH_ELEMS 262144          // 512*512 f16
#define WS_BYTES_MFMA (WS_FLOATS * 4 + (size_t)(AH_ELEMS + 2 * WH_ELEMS) * 2)

// Measurement round: in-kernel repeat factors to lift each kernel above the
// ~40us fill dispatches in the rocprof top-5. Outputs are idempotent.
#define REP_CONV 16
#define REP_PROJ 12
#define REP_SCORES 6
#define REP_CTX 10

#define GLD16(gp, lp)                                                         \
  __builtin_amdgcn_global_load_lds(                                           \
      (const __attribute__((address_space(1))) void*)(gp),                    \
      (__attribute__((address_space(3))) void*)(lp), 16, 0, 0)

// ---------------------------------------------------------------------------
// Kernel 1: f32 -> f16 convert into PRE-SWIZZLED per-batch layout + v.
// ---------------------------------------------------------------------------
__global__ __launch_bounds__(256) void convert_kernel(
    const float* __restrict__ query, const float* __restrict__ keys,
    const float* __restrict__ Wq, const float* __restrict__ Wk,
    const float* __restrict__ la, const float* __restrict__ scalar,
    _Float16* __restrict__ Acvt, _Float16* __restrict__ Wkcvt,
    _Float16* __restrict__ Wqcvt, float* __restrict__ v) {
  int bid = blockIdx.x;
  int t = threadIdx.x;
  if (bid == 1408) {  // v block
    __shared__ float red[4], red2[4];
    for (int rep = 0; rep < REP_CONV; ++rep) {
      float x0 = la[t], x1 = la[t + 256];
      float ss = x0 * x0 + x1 * x1;
#pragma unroll
      for (int o = 1; o < 64; o <<= 1) ss += __shfl_xor(ss, o, 64);
      int wave = t >> 6, lane = t & 63;
      if (lane == 0) red[wave] = ss;
      __syncthreads();
      float tot = red[0] + red[1] + red[2] + red[3];
      float sc = rsqrtf(tot) * scalar[0];
      float v0 = x0 * sc, v1 = x1 * sc;
      v[t] = v0;
      v[t + 256] = v1;
      float sv = v0 + v1;
#pragma unroll
      for (int o = 1; o < 64; o <<= 1) sv += __shfl_xor(sv, o, 64);
      if (lane == 0) red2[wave] = sv;
      __syncthreads();
      if (t == 0) v[512] = red2[0] + red2[1] + red2[2] + red2[3];
      __syncthreads();
      asm volatile("" ::: "memory");
    }
    return;
  }
  const float* src;
  _Float16* dst;
  int r, bb = t & 63;
  if (bid < 1152) {  // A: XCD-pinned per batch
    int b = bid & 7;
    int i = bid >> 3;
    r = i * 4 + (t >> 6);
    src = (r < 512) ? keys + ((size_t)b * 512 + r) * 512
                    : query + ((size_t)b * 64 + (r - 512)) * 512;
    dst = Acvt + ((size_t)b * 576 + r) * 512;
  } else if (bid < 1280) {
    int j = bid - 1152;
    r = j * 4 + (t >> 6);
    src = Wk + (size_t)r * 512;
    dst = Wkcvt + (size_t)r * 512;
  } else {
    int j = bid - 1280;
    r = j * 4 + (t >> 6);
    src = Wq + (size_t)r * 512;
    dst = Wqcvt + (size_t)r * 512;
  }
  int scol = ((bb & 56) | ((bb ^ r) & 7)) * 8;
  for (int rep = 0; rep < REP_CONV; ++rep) {
    float4 x0 = *reinterpret_cast<const float4*>(src + scol);
    float4 x1 = *reinterpret_cast<const float4*>(src + scol + 4);
    half8 o = {(_Float16)x0.x, (_Float16)x0.y, (_Float16)x0.z, (_Float16)x0.w,
               (_Float16)x1.x, (_Float16)x1.y, (_Float16)x1.z, (_Float16)x1.w};
    *reinterpret_cast<half8*>(dst + bb * 8) = o;
    asm volatile("" ::: "memory");
  }
}

// ---------------------------------------------------------------------------
// Kernel 2: MFMA projection (R9 structure), rep-inflated.
// ---------------------------------------------------------------------------
__global__ __launch_bounds__(256) void mfma_proj_kernel(
    const _Float16* __restrict__ Acvt, const _Float16* __restrict__ Wkcvt,
    const _Float16* __restrict__ Wqcvt, const float* __restrict__ bias,
    float* __restrict__ Ek, float* __restrict__ Eq) {
  __shared__ _Float16 sA[2][64][64];
  __shared__ _Float16 sW[2][64][64];
  int lid = blockIdx.x;  // [0,576)
  int b = lid & 7;
  int rr = lid >> 3;
  int mtb = rr % 9;
  int nt = rr / 9;
  int n0 = nt * 64;
  bool isQ = (mtb == 8);
  const _Float16* Wcvt = isQ ? Wqcvt : Wkcvt;
  size_t mrowbase = (size_t)b * 576 + (size_t)mtb * 64;
  int t = threadIdx.x;
  int wave = t >> 6, lane = t & 63;
  int mw = (wave >> 1) * 32, nw = (wave & 1) * 32;
  int lr = lane & 31, g = lane >> 5;
  int arow = mw + lr, wrow = nw + lr;
  int lrow = lane >> 3, lblk = lane & 7;
  const _Float16* gAbase =
      Acvt + (mrowbase + wave * 16 + lrow) * 512 + lblk * 8;
  const _Float16* gWbase =
      Wcvt + ((size_t)(n0 + wave * 16 + lrow)) * 512 + lblk * 8;
  int col = n0 + nw + lr;
  float bv = isQ ? bias[col] : 0.f;

#define STAGE(kt, sel)                                                        \
  {                                                                           \
    int koff = (kt)*64;                                                       \
    GLD16(gAbase + koff, &sA[sel][wave * 16][0]);                             \
    GLD16(gAbase + koff + 8 * 512, &sA[sel][wave * 16 + 8][0]);               \
    GLD16(gWbase + koff, &sW[sel][wave * 16][0]);                             \
    GLD16(gWbase + koff + 8 * 512, &sW[sel][wave * 16 + 8][0]);               \
  }

  for (int rep = 0; rep < REP_PROJ; ++rep) {
    floatx16 acc;
#pragma unroll
    for (int i = 0; i < 16; i++) acc[i] = 0.f;
    STAGE(0, 0);
    for (int kt = 0; kt < 8; kt++) {
      __syncthreads();
      if (kt < 7) STAGE(kt + 1, (kt + 1) & 1);
      int sel = kt & 1;
#pragma unroll
      for (int i = 0; i < 4; i++) {
        int ablk = (((2 * i + g) ^ arow) & 7) * 8 + ((2 * i + g) & ~7) * 8;
        int wblk = (((2 * i + g) ^ wrow) & 7) * 8 + ((2 * i + g) & ~7) * 8;
        half8 af = *reinterpret_cast<const half8*>(&sA[sel][arow][ablk]);
        half8 wf = *reinterpret_cast<const half8*>(&sW[sel][wrow][wblk]);
        acc = __builtin_amdgcn_mfma_f32_32x32x16_f16(af, wf, acc, 0, 0, 0);
      }
    }
#pragma unroll
    for (int r = 0; r < 16; r++) {
      int lrow_out = mtb * 64 + mw + (r & 3) + 8 * (r >> 2) + 4 * g;
      float e = __builtin_amdgcn_exp2f((acc[r] + bv) * C2F);
      if (isQ)
        Eq[((size_t)b * 64 + (lrow_out - 512)) * NU_ + col] = e;
      else
        Ek[((size_t)b * 512 + lrow_out) * NU_ + col] = e;
    }
    __syncthreads();  // all reads of sA/sW done before next rep restages
    asm volatile("" ::: "memory");
  }
#undef STAGE
}

// ---------------------------------------------------------------------------
// Fallback (ws too small): f32 projection writing Eq/Ek, + v kernel
// ---------------------------------------------------------------------------
__global__ __launch_bounds__(512) void compute_v_kernel(
    const float* __restrict__ la, const float* __restrict__ scalar,
    float* __restrict__ v) {
  __shared__ float red[8], red2[8];
  int t = threadIdx.x;
  float x = la[t];
  float ss = x * x;
#pragma unroll
  for (int o = 1; o < 64; o <<= 1) ss += __shfl_xor(ss, o, 64);
  int wave = t >> 6, lane = t & 63;
  if (lane == 0) red[wave] = ss;
  __syncthreads();
  float tot = 0.f;
#pragma unroll
  for (int w = 0; w < 8; w++) tot += red[w];
  float vv = x * rsqrtf(tot) * scalar[0];
  v[t] = vv;
  float sv = vv;
#pragma unroll
  for (int o = 1; o < 64; o <<= 1) sv += __shfl_xor(sv, o, 64);
  if (lane == 0) red2[wave] = sv;
  __syncthreads();
  if (t == 0) {
    float s = 0.f;
#pragma unroll
    for (int w = 0; w < 8; w++) s += red2[w];
    v[512] = s;
  }
}

__global__ __launch_bounds__(256) void proj_gemm_kernel(
    const float* __restrict__ query, const float* __restrict__ keys,
    const float* __restrict__ Wq, const float* __restrict__ Wk,
    const float* __restrict__ bias, float* __restrict__ Eq,
    float* __restrict__ Ek) {
  __shared__ __align__(16) float As[16][68];
  __shared__ __align__(16) float Bs[16][68];
  int mt = blockIdx.x;
  int n0 = blockIdx.y * 64;
  const float* A;
  const float* W;
  float* C;
  bool ub;
  if (mt < 8) {
    A = query + (size_t)mt * 64 * D_;
    W = Wq;
    C = Eq + (size_t)mt * 64 * NU_;
    ub = true;
  } else {
    A = keys + (size_t)(mt - 8) * 64 * D_;
    W = Wk;
    C = Ek + (size_t)(mt - 8) * 64 * NU_;
    ub = false;
  }
  int t = threadIdx.x;
  int tx = t & 15, ty = t >> 4;
  int ld = t & 15, lm = t >> 4;
  float acc[4][4] = {};
  for (int d0 = 0; d0 < D_; d0 += 16) {
#pragma unroll
    for (int r = 0; r < 4; r++) {
      As[ld][lm + 16 * r] = A[(size_t)(lm + 16 * r) * D_ + d0 + ld];
      Bs[ld][lm + 16 * r] = W[(size_t)(n0 + lm + 16 * r) * D_ + d0 + ld];
    }
    __syncthreads();
#pragma unroll
    for (int dd = 0; dd < 16; dd++) {
      float4 a4 = *reinterpret_cast<const float4*>(&As[dd][ty * 4]);
      float4 b4 = *reinterpret_cast<const float4*>(&Bs[dd][tx * 4]);
      float av[4] = {a4.x, a4.y, a4.z, a4.w};
      float bv[4] = {b4.x, b4.y, b4.z, b4.w};
#pragma unroll
      for (int i = 0; i < 4; i++)
#pragma unroll
        for (int j = 0; j < 4; j++)
          acc[i][j] = fmaf(av[i], bv[j], acc[i][j]);
    }
    __syncthreads();
  }
#pragma unroll
  for (int i = 0; i < 4; i++) {
    float4 o;
    float* op = &o.x;
#pragma unroll
    for (int j = 0; j < 4; j++) {
      float val = acc[i][j];
      if (ub) val += bias[n0 + tx * 4 + j];
      op[j] = __builtin_amdgcn_exp2f(val * C2F);
    }
    *reinterpret_cast<float4*>(&C[(size_t)(ty * 4 + i) * NU_ + n0 + tx * 4]) = o;
  }
}

// ---------------------------------------------------------------------------
// Kernel 3: scores (R9 structure), rep-inflated.
// ---------------------------------------------------------------------------
__global__ __launch_bounds__(256) void scores_kernel(
    const float* __restrict__ Eq, const float* __restrict__ Ek,
    const float* __restrict__ v, float* __restrict__ S) {
  __shared__ __align__(16) float sEq[8][NU_];
  __shared__ __align__(16) float sV[NU_];
  __shared__ float sRed[2][8][8];
  int lid = blockIdx.x;
  int b = lid & 7;
  int rrr = lid >> 3;
  int qt = rrr & 7, kt = rrr >> 3;
  int q0 = qt * 8, k0 = kt * 16;
  int t = threadIdx.x;
  const float4* eqsrc =
      reinterpret_cast<const float4*>(Eq + ((size_t)b * Q_ + q0) * NU_);
  int wave = t >> 6, lane = t & 63;
  int uw = wave >> 1, kw = wave & 1;
  int klane = lane >> 3, ulane = lane & 7;
  int k = k0 + kw * 8 + klane;
  const float* ekr = Ek + ((size_t)b * K_ + k) * NU_;

  for (int rep = 0; rep < REP_SCORES; ++rep) {
#pragma unroll
    for (int i = 0; i < 4; i++)
      reinterpret_cast<float4*>(&sEq[0][0])[t + 256 * i] = eqsrc[t + 256 * i];
    if (t < 128)
      reinterpret_cast<float4*>(sV)[t] = reinterpret_cast<const float4*>(v)[t];
    float vtot = v[512];
    __syncthreads();

    float acc[8] = {};
#pragma unroll 2
    for (int j = 0; j < 8; j++) {
      int u = uw * 256 + ulane * 4 + 32 * j;
      float4 ek4 = *reinterpret_cast<const float4*>(ekr + u);
      float4 v4 = *reinterpret_cast<const float4*>(&sV[u]);
#pragma unroll
      for (int qq = 0; qq < 8; qq++) {
        float4 eq4 = *reinterpret_cast<const float4*>(&sEq[qq][u]);
        float p0 = fmaf(eq4.x, ek4.x, 1.f);
        float p1 = fmaf(eq4.y, ek4.y, 1.f);
        float p2 = fmaf(eq4.z, ek4.z, 1.f);
        float p3 = fmaf(eq4.w, ek4.w, 1.f);
        float n01 = fmaf(v4.x, p1, v4.y * p0);
        float n23 = fmaf(v4.z, p3, v4.w * p2);
        float r01 = __builtin_amdgcn_rcpf(p0 * p1);
        float r23 = __builtin_amdgcn_rcpf(p2 * p3);
        acc[qq] = fmaf(n01, r01, acc[qq]);
        acc[qq] = fmaf(n23, r23, acc[qq]);
      }
    }
#pragma unroll
    for (int qq = 0; qq < 8; qq++) {
      acc[qq] += __shfl_xor(acc[qq], 1, 64);
      acc[qq] += __shfl_xor(acc[qq], 2, 64);
      acc[qq] += __shfl_xor(acc[qq], 4, 64);
    }
    if (uw == 1 && ulane == 0) {
#pragma unroll
      for (int qq = 0; qq < 8; qq++) sRed[kw][klane][qq] = acc[qq];
    }
    __syncthreads();
    if (uw == 0 && ulane == 0) {
#pragma unroll
      for (int qq = 0; qq < 8; qq++) {
        float a = acc[qq] + sRed[kw][klane][qq];
        S[((size_t)b * Q_ + q0 + qq) * K_ + k] = fmaf(-2.f, a, vtot);
      }
    }
    __syncthreads();  // sRed consumed before next rep overwrites
    asm volatile("" ::: "memory");
  }
}

// ---------------------------------------------------------------------------
// Kernel 4: softmax + context (R9 structure), rep-inflated.
// ---------------------------------------------------------------------------
__global__ __launch_bounds__(256) void ctx_kernel(
    const float* __restrict__ S, const float* __restrict__ keys,
    float* __restrict__ ctx, float* __restrict__ smx) {
  __shared__ __align__(16) float sS[8][K_];
  __shared__ __align__(16) float sK[2][64][32];
  __shared__ float sPart[3][16][16];
  int lid = blockIdx.x;
  int b = lid & 7;
  int rrr = lid >> 3;
  int qt = rrr & 7, dt = rrr >> 3;
  int q0 = qt * 8, d0 = dt * 32;
  int t = threadIdx.x;
  const float4* ssrc =
      reinterpret_cast<const float4*>(S + ((size_t)b * Q_ + q0) * K_);
  const float* keysb = keys + (size_t)b * K_ * D_ + d0;
  int dg = t & 15, ks = t >> 4;
  int wave = t >> 6, lane = t & 63;

  for (int rep = 0; rep < REP_CTX; ++rep) {
#pragma unroll
    for (int i = 0; i < 4; i++)
      reinterpret_cast<float4*>(&sS[0][0])[t + 256 * i] = ssrc[t + 256 * i];
#pragma unroll
    for (int e = 0; e < 2; e++) {
      int idx = t * 2 + e;
      int row = idx >> 3, c4 = idx & 7;
      *reinterpret_cast<float4*>(&sK[0][row][c4 * 4]) =
          *reinterpret_cast<const float4*>(&keysb[(size_t)row * D_ + c4 * 4]);
    }
    __syncthreads();

    {
      int q = t >> 5, lg = t & 31;
      float m = -1e30f;
      for (int kk = lg; kk < K_; kk += 32) m = fmaxf(m, sS[q][kk]);
#pragma unroll
      for (int o = 1; o < 32; o <<= 1) m = fmaxf(m, __shfl_xor(m, o, 64));
      const float L2E = 1.4426950408889634f;
      float sum = 0.f;
      for (int kk = lg; kk < K_; kk += 32)
        sum += __builtin_amdgcn_exp2f((sS[q][kk] - m) * L2E);
#pragma unroll
      for (int o = 1; o < 32; o <<= 1) sum += __shfl_xor(sum, o, 64);
      if (dt == 0) {
        float inv = 1.f / sum;
        float* dst = smx + ((size_t)b * Q_ + q0 + q) * K_;
        for (int kk = lg; kk < K_; kk += 32)
          dst[kk] = __builtin_amdgcn_exp2f((sS[q][kk] - m) * L2E) * inv;
      }
    }

    float acc[8][2] = {};
    int cur = 0;
    for (int kc = 0; kc < K_; kc += 64) {
      if (kc + 64 < K_) {
        const float* kn = keysb + (size_t)(kc + 64) * D_;
#pragma unroll
        for (int e = 0; e < 2; e++) {
          int idx = t * 2 + e;
          int row = idx >> 3, c4 = idx & 7;
          *reinterpret_cast<float4*>(&sK[cur ^ 1][row][c4 * 4]) =
              *reinterpret_cast<const float4*>(&kn[(size_t)row * D_ + c4 * 4]);
        }
      }
#pragma unroll
      for (int i = 0; i < 4; i++) {
        int kk = ks * 4 + i;
        float2 kv = *reinterpret_cast<const float2*>(&sK[cur][kk][dg * 2]);
#pragma unroll
        for (int qq = 0; qq < 8; qq++) {
          float s = sS[qq][kc + kk];
          acc[qq][0] = fmaf(s, kv.x, acc[qq][0]);
          acc[qq][1] = fmaf(s, kv.y, acc[qq][1]);
        }
      }
      __syncthreads();
      cur ^= 1;
    }
#pragma unroll
    for (int qq = 0; qq < 8; qq++) {
      acc[qq][0] += __shfl_xor(acc[qq][0], 16, 64);
      acc[qq][1] += __shfl_xor(acc[qq][1], 16, 64);
      acc[qq][0] += __shfl_xor(acc[qq][0], 32, 64);
      acc[qq][1] += __shfl_xor(acc[qq][1], 32, 64);
    }
    if (wave > 0 && lane < 16) {
#pragma unroll
      for (int qq = 0; qq < 8; qq++) {
        sPart[wave - 1][lane][qq * 2] = acc[qq][0];
        sPart[wave - 1][lane][qq * 2 + 1] = acc[qq][1];
      }
    }
    __syncthreads();
    if (wave == 0 && lane < 16) {
#pragma unroll
      for (int qq = 0; qq < 8; qq++) {
        float c0 = acc[qq][0] + sPart[0][lane][qq * 2] +
                   sPart[1][lane][qq * 2] + sPart[2][lane][qq * 2];
        float c1 = acc[qq][1] + sPart[0][lane][qq * 2 + 1] +
                   sPart[1][lane][qq * 2 + 1] + sPart[2][lane][qq * 2 + 1];
        float2 o2 = {c0, c1};
        *reinterpret_cast<float2*>(
            &ctx[((size_t)b * Q_ + q0 + qq) * D_ + d0 + lane * 2]) = o2;
      }
    }
    __syncthreads();  // sPart consumed before next rep overwrites
    asm volatile("" ::: "memory");
  }
}

// ---------------------------------------------------------------------------
extern "C" void kernel_launch(void* const* d_in, const int* in_sizes, int n_in,
                              void* d_out, int out_size, void* d_ws,
                              size_t ws_size, hipStream_t stream) {
  const float* query = (const float*)d_in[0];
  const float* keys = (const float*)d_in[1];
  const float* Wq = (const float*)d_in[2];
  const float* Wk = (const float*)d_in[3];
  const float* la = (const float*)d_in[4];
  const float* nscalar = (const float*)d_in[5];
  const float* nbias = (const float*)d_in[6];

  float* out = (float*)d_out;
  float* ctx = out;
  float* smx = out + (size_t)B_ * Q_ * D_;

  float* ws = (float*)d_ws;
  float* v = ws + WS_V;
  float* Eq = ws + WS_EQ;
  float* Ek = ws + WS_EK;
  float* S = ws + WS_S;

  if (ws_size >= (size_t)WS_BYTES_MFMA) {
    _Float16* Acvt = (_Float16*)(ws + WS_FLOATS);
    _Float16* Wkcvt = Acvt + AH_ELEMS;
    _Float16* Wqcvt = Wkcvt + WH_ELEMS;
    convert_kernel<<<1409, 256, 0, stream>>>(query, keys, Wq, Wk, la, nscalar,
                                             Acvt, Wkcvt, Wqcvt, v);
    mfma_proj_kernel<<<576, 256, 0, stream>>>(Acvt, Wkcvt, Wqcvt, nbias, Ek,
                                              Eq);
  } else {
    compute_v_kernel<<<1, 512, 0, stream>>>(la, nscalar, v);
    proj_gemm_kernel<<<dim3(72, 8), 256, 0, stream>>>(query, keys, Wq, Wk,
                                                      nbias, Eq, Ek);
  }
  scores_kernel<<<2048, 256, 0, stream>>>(Eq, Ek, v, S);
  ctx_kernel<<<1024, 256, 0, stream>>>(S, keys, ctx, smx);
}

// Round 11
// 54.639 us; speedup vs baseline: 6.5223x; 6.5223x over previous
//
#include <hip/hip_runtime.h>

#define B_ 8
#define Q_ 64
#define K_ 512
#define NU_ 512
#define D_ 512

typedef __attribute__((ext_vector_type(8))) _Float16 half8;
typedef __attribute__((ext_vector_type(4))) _Float16 half4;
typedef __attribute__((ext_vector_type(16))) float floatx16;

#define C2F 2.8853900817779268f  // 2*log2(e)

// ws float-layout
#define WS_V 0                   // v[0..511], vtot at [512]
#define WS_EQ 640                // Eq: 8*64*512
#define WS_EK (640 + 262144)     // Ek: 8*512*512
#define WS_S (WS_EK + 2097152)   // S raw scores: 8*64*512
#define WS_FLOATS (WS_S + 262144)
#define AH_ELEMS 2359296         // 8 b * 576 rows (512 keys + 64 query) * 512
#define WH_ELEMS 262144          // 512*512 f16
#define WS_BYTES_MFMA (WS_FLOATS * 4 + (size_t)(AH_ELEMS + 2 * WH_ELEMS) * 2)

#define GLD16(gp, lp)                                                         \
  __builtin_amdgcn_global_load_lds(                                           \
      (const __attribute__((address_space(1))) void*)(gp),                    \
      (__attribute__((address_space(3))) void*)(lp), 16, 0, 0)

// ---------------------------------------------------------------------------
// Kernel 1: f32 -> f16 convert into PRE-SWIZZLED per-batch layout + v.
// (unchanged from round 9)
// ---------------------------------------------------------------------------
__global__ __launch_bounds__(256) void convert_kernel(
    const float* __restrict__ query, const float* __restrict__ keys,
    const float* __restrict__ Wq, const float* __restrict__ Wk,
    const float* __restrict__ la, const float* __restrict__ scalar,
    _Float16* __restrict__ Acvt, _Float16* __restrict__ Wkcvt,
    _Float16* __restrict__ Wqcvt, float* __restrict__ v) {
  int bid = blockIdx.x;
  int t = threadIdx.x;
  if (bid == 1408) {  // v block
    __shared__ float red[4], red2[4];
    float x0 = la[t], x1 = la[t + 256];
    float ss = x0 * x0 + x1 * x1;
#pragma unroll
    for (int o = 1; o < 64; o <<= 1) ss += __shfl_xor(ss, o, 64);
    int wave = t >> 6, lane = t & 63;
    if (lane == 0) red[wave] = ss;
    __syncthreads();
    float tot = red[0] + red[1] + red[2] + red[3];
    float sc = rsqrtf(tot) * scalar[0];
    float v0 = x0 * sc, v1 = x1 * sc;
    v[t] = v0;
    v[t + 256] = v1;
    float sv = v0 + v1;
#pragma unroll
    for (int o = 1; o < 64; o <<= 1) sv += __shfl_xor(sv, o, 64);
    if (lane == 0) red2[wave] = sv;
    __syncthreads();
    if (t == 0) v[512] = red2[0] + red2[1] + red2[2] + red2[3];
    return;
  }
  const float* src;
  _Float16* dst;
  int r, bb = t & 63;
  if (bid < 1152) {  // A: XCD-pinned per batch
    int b = bid & 7;
    int i = bid >> 3;
    r = i * 4 + (t >> 6);
    src = (r < 512) ? keys + ((size_t)b * 512 + r) * 512
                    : query + ((size_t)b * 64 + (r - 512)) * 512;
    dst = Acvt + ((size_t)b * 576 + r) * 512;
  } else if (bid < 1280) {
    int j = bid - 1152;
    r = j * 4 + (t >> 6);
    src = Wk + (size_t)r * 512;
    dst = Wkcvt + (size_t)r * 512;
  } else {
    int j = bid - 1280;
    r = j * 4 + (t >> 6);
    src = Wq + (size_t)r * 512;
    dst = Wqcvt + (size_t)r * 512;
  }
  int scol = ((bb & 56) | ((bb ^ r) & 7)) * 8;
  float4 x0 = *reinterpret_cast<const float4*>(src + scol);
  float4 x1 = *reinterpret_cast<const float4*>(src + scol + 4);
  half8 o = {(_Float16)x0.x, (_Float16)x0.y, (_Float16)x0.z, (_Float16)x0.w,
             (_Float16)x1.x, (_Float16)x1.y, (_Float16)x1.z, (_Float16)x1.w};
  *reinterpret_cast<half8*>(dst + bb * 8) = o;
}

// ---------------------------------------------------------------------------
// Kernel 2: MFMA projection (unchanged from round 9).
// ---------------------------------------------------------------------------
__global__ __launch_bounds__(256) void mfma_proj_kernel(
    const _Float16* __restrict__ Acvt, const _Float16* __restrict__ Wkcvt,
    const _Float16* __restrict__ Wqcvt, const float* __restrict__ bias,
    float* __restrict__ Ek, float* __restrict__ Eq) {
  __shared__ _Float16 sA[2][64][64];
  __shared__ _Float16 sW[2][64][64];
  int lid = blockIdx.x;  // [0,576)
  int b = lid & 7;
  int rr = lid >> 3;
  int mtb = rr % 9;
  int nt = rr / 9;
  int n0 = nt * 64;
  bool isQ = (mtb == 8);
  const _Float16* Wcvt = isQ ? Wqcvt : Wkcvt;
  size_t mrowbase = (size_t)b * 576 + (size_t)mtb * 64;
  int t = threadIdx.x;
  int wave = t >> 6, lane = t & 63;
  int mw = (wave >> 1) * 32, nw = (wave & 1) * 32;
  int lr = lane & 31, g = lane >> 5;
  int arow = mw + lr, wrow = nw + lr;
  int lrow = lane >> 3, lblk = lane & 7;
  const _Float16* gAbase =
      Acvt + (mrowbase + wave * 16 + lrow) * 512 + lblk * 8;
  const _Float16* gWbase =
      Wcvt + ((size_t)(n0 + wave * 16 + lrow)) * 512 + lblk * 8;

  floatx16 acc;
#pragma unroll
  for (int i = 0; i < 16; i++) acc[i] = 0.f;

#define STAGE(kt, sel)                                                        \
  {                                                                           \
    int koff = (kt)*64;                                                       \
    GLD16(gAbase + koff, &sA[sel][wave * 16][0]);                             \
    GLD16(gAbase + koff + 8 * 512, &sA[sel][wave * 16 + 8][0]);               \
    GLD16(gWbase + koff, &sW[sel][wave * 16][0]);                             \
    GLD16(gWbase + koff + 8 * 512, &sW[sel][wave * 16 + 8][0]);               \
  }

  STAGE(0, 0);
  for (int kt = 0; kt < 8; kt++) {
    __syncthreads();
    if (kt < 7) STAGE(kt + 1, (kt + 1) & 1);
    int sel = kt & 1;
#pragma unroll
    for (int i = 0; i < 4; i++) {
      int ablk = (((2 * i + g) ^ arow) & 7) * 8 + ((2 * i + g) & ~7) * 8;
      int wblk = (((2 * i + g) ^ wrow) & 7) * 8 + ((2 * i + g) & ~7) * 8;
      half8 af = *reinterpret_cast<const half8*>(&sA[sel][arow][ablk]);
      half8 wf = *reinterpret_cast<const half8*>(&sW[sel][wrow][wblk]);
      acc = __builtin_amdgcn_mfma_f32_32x32x16_f16(af, wf, acc, 0, 0, 0);
    }
  }
#undef STAGE
  int col = n0 + nw + lr;
  float bv = isQ ? bias[col] : 0.f;
#pragma unroll
  for (int r = 0; r < 16; r++) {
    int lrow_out = mtb * 64 + mw + (r & 3) + 8 * (r >> 2) + 4 * g;
    float e = __builtin_amdgcn_exp2f((acc[r] + bv) * C2F);
    if (isQ)
      Eq[((size_t)b * 64 + (lrow_out - 512)) * NU_ + col] = e;
    else
      Ek[((size_t)b * 512 + lrow_out) * NU_ + col] = e;
  }
}

// ---------------------------------------------------------------------------
// Fallback (ws too small): f32 projection writing Eq/Ek, + v kernel
// ---------------------------------------------------------------------------
__global__ __launch_bounds__(512) void compute_v_kernel(
    const float* __restrict__ la, const float* __restrict__ scalar,
    float* __restrict__ v) {
  __shared__ float red[8], red2[8];
  int t = threadIdx.x;
  float x = la[t];
  float ss = x * x;
#pragma unroll
  for (int o = 1; o < 64; o <<= 1) ss += __shfl_xor(ss, o, 64);
  int wave = t >> 6, lane = t & 63;
  if (lane == 0) red[wave] = ss;
  __syncthreads();
  float tot = 0.f;
#pragma unroll
  for (int w = 0; w < 8; w++) tot += red[w];
  float vv = x * rsqrtf(tot) * scalar[0];
  v[t] = vv;
  float sv = vv;
#pragma unroll
  for (int o = 1; o < 64; o <<= 1) sv += __shfl_xor(sv, o, 64);
  if (lane == 0) red2[wave] = sv;
  __syncthreads();
  if (t == 0) {
    float s = 0.f;
#pragma unroll
    for (int w = 0; w < 8; w++) s += red2[w];
    v[512] = s;
  }
}

__global__ __launch_bounds__(256) void proj_gemm_kernel(
    const float* __restrict__ query, const float* __restrict__ keys,
    const float* __restrict__ Wq, const float* __restrict__ Wk,
    const float* __restrict__ bias, float* __restrict__ Eq,
    float* __restrict__ Ek) {
  __shared__ __align__(16) float As[16][68];
  __shared__ __align__(16) float Bs[16][68];
  int mt = blockIdx.x;
  int n0 = blockIdx.y * 64;
  const float* A;
  const float* W;
  float* C;
  bool ub;
  if (mt < 8) {
    A = query + (size_t)mt * 64 * D_;
    W = Wq;
    C = Eq + (size_t)mt * 64 * NU_;
    ub = true;
  } else {
    A = keys + (size_t)(mt - 8) * 64 * D_;
    W = Wk;
    C = Ek + (size_t)(mt - 8) * 64 * NU_;
    ub = false;
  }
  int t = threadIdx.x;
  int tx = t & 15, ty = t >> 4;
  int ld = t & 15, lm = t >> 4;
  float acc[4][4] = {};
  for (int d0 = 0; d0 < D_; d0 += 16) {
#pragma unroll
    for (int r = 0; r < 4; r++) {
      As[ld][lm + 16 * r] = A[(size_t)(lm + 16 * r) * D_ + d0 + ld];
      Bs[ld][lm + 16 * r] = W[(size_t)(n0 + lm + 16 * r) * D_ + d0 + ld];
    }
    __syncthreads();
#pragma unroll
    for (int dd = 0; dd < 16; dd++) {
      float4 a4 = *reinterpret_cast<const float4*>(&As[dd][ty * 4]);
      float4 b4 = *reinterpret_cast<const float4*>(&Bs[dd][tx * 4]);
      float av[4] = {a4.x, a4.y, a4.z, a4.w};
      float bv[4] = {b4.x, b4.y, b4.z, b4.w};
#pragma unroll
      for (int i = 0; i < 4; i++)
#pragma unroll
        for (int j = 0; j < 4; j++)
          acc[i][j] = fmaf(av[i], bv[j], acc[i][j]);
    }
    __syncthreads();
  }
#pragma unroll
  for (int i = 0; i < 4; i++) {
    float4 o;
    float* op = &o.x;
#pragma unroll
    for (int j = 0; j < 4; j++) {
      float val = acc[i][j];
      if (ub) val += bias[n0 + tx * 4 + j];
      op[j] = __builtin_amdgcn_exp2f(val * C2F);
    }
    *reinterpret_cast<float4*>(&C[(size_t)(ty * 4 + i) * NU_ + n0 + tx * 4]) = o;
  }
}

// ---------------------------------------------------------------------------
// Kernel 3: scores (unchanged from round 9).
// ---------------------------------------------------------------------------
__global__ __launch_bounds__(256) void scores_kernel(
    const float* __restrict__ Eq, const float* __restrict__ Ek,
    const float* __restrict__ v, float* __restrict__ S) {
  __shared__ __align__(16) float sEq[8][NU_];
  __shared__ __align__(16) float sV[NU_];
  __shared__ float sRed[2][8][8];
  int lid = blockIdx.x;
  int b = lid & 7;
  int rrr = lid >> 3;
  int qt = rrr & 7, kt = rrr >> 3;
  int q0 = qt * 8, k0 = kt * 16;
  int t = threadIdx.x;
  const float4* eqsrc =
      reinterpret_cast<const float4*>(Eq + ((size_t)b * Q_ + q0) * NU_);
#pragma unroll
  for (int i = 0; i < 4; i++)
    reinterpret_cast<float4*>(&sEq[0][0])[t + 256 * i] = eqsrc[t + 256 * i];
  if (t < 128)
    reinterpret_cast<float4*>(sV)[t] = reinterpret_cast<const float4*>(v)[t];
  float vtot = v[512];
  __syncthreads();

  int wave = t >> 6, lane = t & 63;
  int uw = wave >> 1, kw = wave & 1;
  int klane = lane >> 3, ulane = lane & 7;
  int k = k0 + kw * 8 + klane;
  const float* ekr = Ek + ((size_t)b * K_ + k) * NU_;
  float acc[8] = {};
#pragma unroll 2
  for (int j = 0; j < 8; j++) {
    int u = uw * 256 + ulane * 4 + 32 * j;
    float4 ek4 = *reinterpret_cast<const float4*>(ekr + u);
    float4 v4 = *reinterpret_cast<const float4*>(&sV[u]);
#pragma unroll
    for (int qq = 0; qq < 8; qq++) {
      float4 eq4 = *reinterpret_cast<const float4*>(&sEq[qq][u]);
      float p0 = fmaf(eq4.x, ek4.x, 1.f);
      float p1 = fmaf(eq4.y, ek4.y, 1.f);
      float p2 = fmaf(eq4.z, ek4.z, 1.f);
      float p3 = fmaf(eq4.w, ek4.w, 1.f);
      float n01 = fmaf(v4.x, p1, v4.y * p0);
      float n23 = fmaf(v4.z, p3, v4.w * p2);
      float r01 = __builtin_amdgcn_rcpf(p0 * p1);
      float r23 = __builtin_amdgcn_rcpf(p2 * p3);
      acc[qq] = fmaf(n01, r01, acc[qq]);
      acc[qq] = fmaf(n23, r23, acc[qq]);
    }
  }
#pragma unroll
  for (int qq = 0; qq < 8; qq++) {
    acc[qq] += __shfl_xor(acc[qq], 1, 64);
    acc[qq] += __shfl_xor(acc[qq], 2, 64);
    acc[qq] += __shfl_xor(acc[qq], 4, 64);
  }
  if (uw == 1 && ulane == 0) {
#pragma unroll
    for (int qq = 0; qq < 8; qq++) sRed[kw][klane][qq] = acc[qq];
  }
  __syncthreads();
  if (uw == 0 && ulane == 0) {
#pragma unroll
    for (int qq = 0; qq < 8; qq++) {
      float a = acc[qq] + sRed[kw][klane][qq];
      S[((size_t)b * Q_ + q0 + qq) * K_ + k] = fmaf(-2.f, a, vtot);
    }
  }
}

// ---------------------------------------------------------------------------
// Kernel 4: softmax (dt==0 writes smx) + context — RESTRUCTURED.
// Block = (b, qt, dt32). Thread owns dg = t&7 (4 d's), ksl = t>>3 (2 k's per
// 64-k chunk). Per chunk: 2 b128 kv loads (registers) + 8 b64 sS reads +
// 64 fma. sK padded to [64][36] (144B row stride) -> conflict-free staging.
// ---------------------------------------------------------------------------
__global__ __launch_bounds__(256) void ctx_kernel(
    const float* __restrict__ S, const float* __restrict__ keys,
    float* __restrict__ ctx, float* __restrict__ smx) {
  __shared__ __align__(16) float sS[8][K_];      // 16 KB
  __shared__ __align__(16) float sK[2][64][36];  // 18.4 KB (padded)
  __shared__ float sPart[3][8][8][4];            // 3 KB [wave-1][dg][qq][d]
  int lid = blockIdx.x;
  int b = lid & 7;
  int rrr = lid >> 3;
  int qt = rrr & 7, dt = rrr >> 3;  // dt [0,16)
  int q0 = qt * 8, d0 = dt * 32;
  int t = threadIdx.x;
  const float4* ssrc =
      reinterpret_cast<const float4*>(S + ((size_t)b * Q_ + q0) * K_);
#pragma unroll
  for (int i = 0; i < 4; i++)
    reinterpret_cast<float4*>(&sS[0][0])[t + 256 * i] = ssrc[t + 256 * i];
  const float* keysb = keys + (size_t)b * K_ * D_ + d0;
#pragma unroll
  for (int e = 0; e < 2; e++) {
    int idx = t * 2 + e;
    int row = idx >> 3, c4 = idx & 7;
    *reinterpret_cast<float4*>(&sK[0][row][c4 * 4]) =
        *reinterpret_cast<const float4*>(&keysb[(size_t)row * D_ + c4 * 4]);
  }
  __syncthreads();

  // ---- softmax (32-lane group per q) ----
  {
    int q = t >> 5, lg = t & 31;
    float m = -1e30f;
    for (int kk = lg; kk < K_; kk += 32) m = fmaxf(m, sS[q][kk]);
#pragma unroll
    for (int o = 1; o < 32; o <<= 1) m = fmaxf(m, __shfl_xor(m, o, 64));
    const float L2E = 1.4426950408889634f;
    float sum = 0.f;
    for (int kk = lg; kk < K_; kk += 32)
      sum += __builtin_amdgcn_exp2f((sS[q][kk] - m) * L2E);
#pragma unroll
    for (int o = 1; o < 32; o <<= 1) sum += __shfl_xor(sum, o, 64);
    if (dt == 0) {
      float inv = 1.f / sum;
      float* dst = smx + ((size_t)b * Q_ + q0 + q) * K_;
      for (int kk = lg; kk < K_; kk += 32)
        dst[kk] = __builtin_amdgcn_exp2f((sS[q][kk] - m) * L2E) * inv;
    }
  }

  // ---- context: acc[8q][4d], 32-way k-split (2 k per thread per chunk) ----
  int dg = t & 7, ksl = t >> 3;
  float acc[8][4] = {};
  int cur = 0;
  for (int kc = 0; kc < K_; kc += 64) {
    if (kc + 64 < K_) {
      const float* kn = keysb + (size_t)(kc + 64) * D_;
#pragma unroll
      for (int e = 0; e < 2; e++) {
        int idx = t * 2 + e;
        int row = idx >> 3, c4 = idx & 7;
        *reinterpret_cast<float4*>(&sK[cur ^ 1][row][c4 * 4]) =
            *reinterpret_cast<const float4*>(&kn[(size_t)row * D_ + c4 * 4]);
      }
    }
    int k0l = ksl * 2;
    float4 kv0 = *reinterpret_cast<const float4*>(&sK[cur][k0l][dg * 4]);
    float4 kv1 = *reinterpret_cast<const float4*>(&sK[cur][k0l + 1][dg * 4]);
    float kv0a[4] = {kv0.x, kv0.y, kv0.z, kv0.w};
    float kv1a[4] = {kv1.x, kv1.y, kv1.z, kv1.w};
#pragma unroll
    for (int qq = 0; qq < 8; qq++) {
      float2 s2 = *reinterpret_cast<const float2*>(&sS[qq][kc + k0l]);
#pragma unroll
      for (int d = 0; d < 4; d++)
        acc[qq][d] = fmaf(s2.x, kv0a[d], fmaf(s2.y, kv1a[d], acc[qq][d]));
    }
    __syncthreads();
    cur ^= 1;
  }
  // reduce over the 32 k-split groups: lane bits 3,4,5 then cross-wave LDS
  int wave = t >> 6, lane = t & 63;
#pragma unroll
  for (int qq = 0; qq < 8; qq++)
#pragma unroll
    for (int d = 0; d < 4; d++) {
      acc[qq][d] += __shfl_xor(acc[qq][d], 8, 64);
      acc[qq][d] += __shfl_xor(acc[qq][d], 16, 64);
      acc[qq][d] += __shfl_xor(acc[qq][d], 32, 64);
    }
  if (wave > 0 && lane < 8) {
#pragma unroll
    for (int qq = 0; qq < 8; qq++) {
      float4 p = {acc[qq][0], acc[qq][1], acc[qq][2], acc[qq][3]};
      *reinterpret_cast<float4*>(&sPart[wave - 1][lane][qq][0]) = p;
    }
  }
  __syncthreads();
  if (wave == 0 && lane < 8) {
#pragma unroll
    for (int qq = 0; qq < 8; qq++) {
      float4 p0 = *reinterpret_cast<const float4*>(&sPart[0][lane][qq][0]);
      float4 p1 = *reinterpret_cast<const float4*>(&sPart[1][lane][qq][0]);
      float4 p2 = *reinterpret_cast<const float4*>(&sPart[2][lane][qq][0]);
      float4 o;
      o.x = acc[qq][0] + p0.x + p1.x + p2.x;
      o.y = acc[qq][1] + p0.y + p1.y + p2.y;
      o.z = acc[qq][2] + p0.z + p1.z + p2.z;
      o.w = acc[qq][3] + p0.w + p1.w + p2.w;
      *reinterpret_cast<float4*>(
          &ctx[((size_t)b * Q_ + q0 + qq) * D_ + d0 + lane * 4]) = o;
    }
  }
}

// ---------------------------------------------------------------------------
extern "C" void kernel_launch(void* const* d_in, const int* in_sizes, int n_in,
                              void* d_out, int out_size, void* d_ws,
                              size_t ws_size, hipStream_t stream) {
  const float* query = (const float*)d_in[0];
  const float* keys = (const float*)d_in[1];
  const float* Wq = (const float*)d_in[2];
  const float* Wk = (const float*)d_in[3];
  const float* la = (const float*)d_in[4];
  const float* nscalar = (const float*)d_in[5];
  const float* nbias = (const float*)d_in[6];

  float* out = (float*)d_out;
  float* ctx = out;
  float* smx = out + (size_t)B_ * Q_ * D_;

  float* ws = (float*)d_ws;
  float* v = ws + WS_V;
  float* Eq = ws + WS_EQ;
  float* Ek = ws + WS_EK;
  float* S = ws + WS_S;

  if (ws_size >= (size_t)WS_BYTES_MFMA) {
    _Float16* Acvt = (_Float16*)(ws + WS_FLOATS);
    _Float16* Wkcvt = Acvt + AH_ELEMS;
    _Float16* Wqcvt = Wkcvt + WH_ELEMS;
    convert_kernel<<<1409, 256, 0, stream>>>(query, keys, Wq, Wk, la, nscalar,
                                             Acvt, Wkcvt, Wqcvt, v);
    mfma_proj_kernel<<<576, 256, 0, stream>>>(Acvt, Wkcvt, Wqcvt, nbias, Ek,
                                              Eq);
  } else {
    compute_v_kernel<<<1, 512, 0, stream>>>(la, nscalar, v);
    proj_gemm_kernel<<<dim3(72, 8), 256, 0, stream>>>(query, keys, Wq, Wk,
                                                      nbias, Eq, Ek);
  }
  scores_kernel<<<2048, 256, 0, stream>>>(Eq, Ek, v, S);
  ctx_kernel<<<1024, 256, 0, stream>>>(S, keys, ctx, smx);
}

// Round 12
// 43.833 us; speedup vs baseline: 8.1302x; 1.2465x over previous
//
#include <hip/hip_runtime.h>

#define B_ 8
#define Q_ 64
#define K_ 512
#define NU_ 512
#define D_ 512

typedef __attribute__((ext_vector_type(8))) _Float16 half8;
typedef __attribute__((ext_vector_type(16))) float floatx16;

#define C2F 2.8853900817779268f  // 2*log2(e)

// ws float region
#define WS_V 0                   // v[0..511], vtot at [512]
#define WS_EQ 640                // Eq: 8*64*512 f32
#define WS_EK (640 + 262144)     // Ek: 8*512*512 f32
#define WS_FLOATS (WS_EK + 2097152)
// ws half region (after floats)
#define ACVT_ELEMS 2359296  // 8 b * 576 rows (512 keys + 64 query) * 512
#define W_ELEMS 262144      // 512*512
#define KT_ELEMS 2097152    // keysT: 8 b * 512 d * 512 k
#define SH_ELEMS 262144     // Sh: 8 b * 64 q * 512 k

#define GLD16(gp, lp)                                                         \
  __builtin_amdgcn_global_load_lds(                                           \
      (const __attribute__((address_space(1))) void*)(gp),                    \
      (__attribute__((address_space(3))) void*)(lp), 16, 0, 0)

// 16B-block swizzle (involution): dst block swz(B,row) holds logical block B.
__device__ __forceinline__ int swz(int bb, int row) {
  return (bb & 56) | ((bb ^ row) & 7);
}

// ---------------------------------------------------------------------------
// Kernel 1: f32 -> f16 convert into PRE-SWIZZLED per-batch layout + keysT
// transpose + v. Blocks: A [0,1152), Wk [1152,1280), Wq [1280,1408),
// keysT-transpose [1408,1920), v = 1920. All A/T blocks XCD-pinned (b=bid&7).
// ---------------------------------------------------------------------------
__global__ __launch_bounds__(256) void convert_kernel(
    const float* __restrict__ query, const float* __restrict__ keys,
    const float* __restrict__ Wq, const float* __restrict__ Wk,
    const float* __restrict__ la, const float* __restrict__ scalar,
    _Float16* __restrict__ Acvt, _Float16* __restrict__ Wkcvt,
    _Float16* __restrict__ Wqcvt, _Float16* __restrict__ keysT,
    float* __restrict__ v) {
  int bid = blockIdx.x;
  int t = threadIdx.x;
  __shared__ float red[4], red2[4];
  __shared__ _Float16 sT[64][72];
  if (bid == 1920) {  // v block
    float x0 = la[t], x1 = la[t + 256];
    float ss = x0 * x0 + x1 * x1;
#pragma unroll
    for (int o = 1; o < 64; o <<= 1) ss += __shfl_xor(ss, o, 64);
    int wave = t >> 6, lane = t & 63;
    if (lane == 0) red[wave] = ss;
    __syncthreads();
    float tot = red[0] + red[1] + red[2] + red[3];
    float sc = rsqrtf(tot) * scalar[0];
    float v0 = x0 * sc, v1 = x1 * sc;
    v[t] = v0;
    v[t + 256] = v1;
    float sv = v0 + v1;
#pragma unroll
    for (int o = 1; o < 64; o <<= 1) sv += __shfl_xor(sv, o, 64);
    if (lane == 0) red2[wave] = sv;
    __syncthreads();
    if (t == 0) v[512] = red2[0] + red2[1] + red2[2] + red2[3];
    return;
  }
  if (bid >= 1408) {  // keysT transpose blocks
    int j = bid - 1408;  // [0,512)
    int b = j & 7;
    int tile = j >> 3;  // [0,64)
    int kt = tile & 7, dtt = tile >> 3;
    int k0 = kt * 64, d0 = dtt * 64;
    const float* kb_ = keys + ((size_t)b * 512 + k0) * 512 + d0;
    int rl = t >> 4;        // 0..15
    int cl = (t & 15) * 4;  // 0..60
#pragma unroll
    for (int p = 0; p < 4; p++) {
      float4 x =
          *reinterpret_cast<const float4*>(kb_ + (size_t)(rl + 16 * p) * 512 + cl);
      sT[cl + 0][rl + 16 * p] = (_Float16)x.x;
      sT[cl + 1][rl + 16 * p] = (_Float16)x.y;
      sT[cl + 2][rl + 16 * p] = (_Float16)x.z;
      sT[cl + 3][rl + 16 * p] = (_Float16)x.w;
    }
    __syncthreads();
    int drl = t >> 2;  // 0..63
    int drow = d0 + drl;
#pragma unroll
    for (int e = 0; e < 2; e++) {
      int kb2 = (t & 3) * 2 + e;  // local 16B block 0..7
      int bb = (k0 >> 3) + kb2;   // global k block
      int sb = swz(bb, drow);
      half8 o = *reinterpret_cast<const half8*>(&sT[drl][kb2 * 8]);
      *reinterpret_cast<half8*>(keysT + ((size_t)b * 512 + drow) * 512 + sb * 8) = o;
    }
    return;
  }
  const float* src;
  _Float16* dst;
  int r, bb = t & 63;
  if (bid < 1152) {  // A: XCD-pinned per batch
    int b = bid & 7;
    int i = bid >> 3;
    r = i * 4 + (t >> 6);  // local row [0,576)
    src = (r < 512) ? keys + ((size_t)b * 512 + r) * 512
                    : query + ((size_t)b * 64 + (r - 512)) * 512;
    dst = Acvt + ((size_t)b * 576 + r) * 512;
  } else if (bid < 1280) {
    int j = bid - 1152;
    r = j * 4 + (t >> 6);
    src = Wk + (size_t)r * 512;
    dst = Wkcvt + (size_t)r * 512;
  } else {
    int j = bid - 1280;
    r = j * 4 + (t >> 6);
    src = Wq + (size_t)r * 512;
    dst = Wqcvt + (size_t)r * 512;
  }
  int scol = swz(bb, r) * 8;
  float4 x0 = *reinterpret_cast<const float4*>(src + scol);
  float4 x1 = *reinterpret_cast<const float4*>(src + scol + 4);
  half8 o = {(_Float16)x0.x, (_Float16)x0.y, (_Float16)x0.z, (_Float16)x0.w,
             (_Float16)x1.x, (_Float16)x1.y, (_Float16)x1.z, (_Float16)x1.w};
  *reinterpret_cast<half8*>(dst + bb * 8) = o;
}

// ---------------------------------------------------------------------------
// Kernel 2: MFMA projection (unchanged from round 9). XCD-pinned.
// ---------------------------------------------------------------------------
__global__ __launch_bounds__(256) void mfma_proj_kernel(
    const _Float16* __restrict__ Acvt, const _Float16* __restrict__ Wkcvt,
    const _Float16* __restrict__ Wqcvt, const float* __restrict__ bias,
    float* __restrict__ Ek, float* __restrict__ Eq) {
  __shared__ _Float16 sA[2][64][64];
  __shared__ _Float16 sW[2][64][64];
  int lid = blockIdx.x;  // [0,576)
  int b = lid & 7;
  int rr = lid >> 3;
  int mtb = rr % 9;
  int nt = rr / 9;
  int n0 = nt * 64;
  bool isQ = (mtb == 8);
  const _Float16* Wcvt = isQ ? Wqcvt : Wkcvt;
  size_t mrowbase = (size_t)b * 576 + (size_t)mtb * 64;
  int t = threadIdx.x;
  int wave = t >> 6, lane = t & 63;
  int mw = (wave >> 1) * 32, nw = (wave & 1) * 32;
  int lr = lane & 31, g = lane >> 5;
  int arow = mw + lr, wrow = nw + lr;
  int lrow = lane >> 3, lblk = lane & 7;
  const _Float16* gAbase = Acvt + (mrowbase + wave * 16 + lrow) * 512 + lblk * 8;
  const _Float16* gWbase =
      Wcvt + ((size_t)(n0 + wave * 16 + lrow)) * 512 + lblk * 8;

  floatx16 acc;
#pragma unroll
  for (int i = 0; i < 16; i++) acc[i] = 0.f;

#define STAGE(kt, sel)                                                        \
  {                                                                           \
    int koff = (kt)*64;                                                       \
    GLD16(gAbase + koff, &sA[sel][wave * 16][0]);                             \
    GLD16(gAbase + koff + 8 * 512, &sA[sel][wave * 16 + 8][0]);               \
    GLD16(gWbase + koff, &sW[sel][wave * 16][0]);                             \
    GLD16(gWbase + koff + 8 * 512, &sW[sel][wave * 16 + 8][0]);               \
  }

  STAGE(0, 0);
  for (int kt = 0; kt < 8; kt++) {
    __syncthreads();
    if (kt < 7) STAGE(kt + 1, (kt + 1) & 1);
    int sel = kt & 1;
#pragma unroll
    for (int i = 0; i < 4; i++) {
      int ablk = (((2 * i + g) ^ arow) & 7) * 8 + ((2 * i + g) & ~7) * 8;
      int wblk = (((2 * i + g) ^ wrow) & 7) * 8 + ((2 * i + g) & ~7) * 8;
      half8 af = *reinterpret_cast<const half8*>(&sA[sel][arow][ablk]);
      half8 wf = *reinterpret_cast<const half8*>(&sW[sel][wrow][wblk]);
      acc = __builtin_amdgcn_mfma_f32_32x32x16_f16(af, wf, acc, 0, 0, 0);
    }
  }
#undef STAGE
  int col = n0 + nw + lr;
  float bv = isQ ? bias[col] : 0.f;
#pragma unroll
  for (int r = 0; r < 16; r++) {
    int lrow_out = mtb * 64 + mw + (r & 3) + 8 * (r >> 2) + 4 * g;
    float e = __builtin_amdgcn_exp2f((acc[r] + bv) * C2F);
    if (isQ)
      Eq[((size_t)b * 64 + (lrow_out - 512)) * NU_ + col] = e;
    else
      Ek[((size_t)b * 512 + lrow_out) * NU_ + col] = e;
  }
}

// ---------------------------------------------------------------------------
// Kernel 3: scores (R9 core); epilogue writes Sh f16 pre-swizzled.
// S[q,k] = vtot - 2 * sum_u v[u] / (1 + Eq[q,u]*Ek[k,u])
// ---------------------------------------------------------------------------
__global__ __launch_bounds__(256) void scores_kernel(
    const float* __restrict__ Eq, const float* __restrict__ Ek,
    const float* __restrict__ v, _Float16* __restrict__ Sh) {
  __shared__ __align__(16) float sEq[8][NU_];
  __shared__ __align__(16) float sV[NU_];
  __shared__ float sRed[2][8][8];
  int lid = blockIdx.x;
  int b = lid & 7;
  int rrr = lid >> 3;
  int qt = rrr & 7, kt = rrr >> 3;
  int q0 = qt * 8, k0 = kt * 16;
  int t = threadIdx.x;
  const float4* eqsrc =
      reinterpret_cast<const float4*>(Eq + ((size_t)b * Q_ + q0) * NU_);
#pragma unroll
  for (int i = 0; i < 4; i++)
    reinterpret_cast<float4*>(&sEq[0][0])[t + 256 * i] = eqsrc[t + 256 * i];
  if (t < 128)
    reinterpret_cast<float4*>(sV)[t] = reinterpret_cast<const float4*>(v)[t];
  float vtot = v[512];
  __syncthreads();

  int wave = t >> 6, lane = t & 63;
  int uw = wave >> 1, kw = wave & 1;
  int klane = lane >> 3, ulane = lane & 7;
  int k = k0 + kw * 8 + klane;
  const float* ekr = Ek + ((size_t)b * K_ + k) * NU_;
  float acc[8] = {};
#pragma unroll 2
  for (int j = 0; j < 8; j++) {
    int u = uw * 256 + ulane * 4 + 32 * j;
    float4 ek4 = *reinterpret_cast<const float4*>(ekr + u);
    float4 v4 = *reinterpret_cast<const float4*>(&sV[u]);
#pragma unroll
    for (int qq = 0; qq < 8; qq++) {
      float4 eq4 = *reinterpret_cast<const float4*>(&sEq[qq][u]);
      float p0 = fmaf(eq4.x, ek4.x, 1.f);
      float p1 = fmaf(eq4.y, ek4.y, 1.f);
      float p2 = fmaf(eq4.z, ek4.z, 1.f);
      float p3 = fmaf(eq4.w, ek4.w, 1.f);
      float n01 = fmaf(v4.x, p1, v4.y * p0);
      float n23 = fmaf(v4.z, p3, v4.w * p2);
      float r01 = __builtin_amdgcn_rcpf(p0 * p1);
      float r23 = __builtin_amdgcn_rcpf(p2 * p3);
      acc[qq] = fmaf(n01, r01, acc[qq]);
      acc[qq] = fmaf(n23, r23, acc[qq]);
    }
  }
#pragma unroll
  for (int qq = 0; qq < 8; qq++) {
    acc[qq] += __shfl_xor(acc[qq], 1, 64);
    acc[qq] += __shfl_xor(acc[qq], 2, 64);
    acc[qq] += __shfl_xor(acc[qq], 4, 64);
  }
  if (uw == 1 && ulane == 0) {
#pragma unroll
    for (int qq = 0; qq < 8; qq++) sRed[kw][klane][qq] = acc[qq];
  }
  __syncthreads();
  if (uw == 0 && ulane == 0) {
#pragma unroll
    for (int qq = 0; qq < 8; qq++) {
      float a = acc[qq] + sRed[kw][klane][qq];
      float sval = fmaf(-2.f, a, vtot);
      int row = q0 + qq;
      int sb = swz(k >> 3, row);
      Sh[((size_t)b * 64 + row) * 512 + sb * 8 + (k & 7)] = (_Float16)sval;
    }
  }
}

// ---------------------------------------------------------------------------
// Kernel 4: ctx via MFMA (blocks 0..63: b=bid&7, nt=bid>>3) + softmax
// (blocks 64..127: reads Sh, writes smx). ctx = Sh @ keysT^T per batch,
// exact clone of the proj template (gld_lds + XOR-swizzled reads).
// ---------------------------------------------------------------------------
__global__ __launch_bounds__(256) void ctxsm_kernel(
    const _Float16* __restrict__ Sh, const _Float16* __restrict__ keysT,
    float* __restrict__ ctx, float* __restrict__ smx) {
  __shared__ _Float16 sA[2][64][64];
  __shared__ _Float16 sW[2][64][64];
  int bid = blockIdx.x;
  int t = threadIdx.x;
  if (bid >= 64) {  // ---- softmax blocks ----
    int idx = bid - 64;
    int b = idx & 7, qt = idx >> 3;
    int q = qt * 8 + (t >> 5), lg = t & 31;
    const _Float16* srow = Sh + ((size_t)b * 64 + q) * 512;
    float sv[16];
#pragma unroll
    for (int ii = 0; ii < 16; ii++) {
      int kk = lg + ii * 32;
      int sb = swz(kk >> 3, q);
      sv[ii] = (float)srow[sb * 8 + (kk & 7)];
    }
    float m = sv[0];
#pragma unroll
    for (int ii = 1; ii < 16; ii++) m = fmaxf(m, sv[ii]);
#pragma unroll
    for (int o = 1; o < 32; o <<= 1) m = fmaxf(m, __shfl_xor(m, o, 64));
    const float L2E = 1.4426950408889634f;
    float e[16], sum = 0.f;
#pragma unroll
    for (int ii = 0; ii < 16; ii++) {
      e[ii] = __builtin_amdgcn_exp2f((sv[ii] - m) * L2E);
      sum += e[ii];
    }
#pragma unroll
    for (int o = 1; o < 32; o <<= 1) sum += __shfl_xor(sum, o, 64);
    float inv = 1.f / sum;
    float* dst = smx + ((size_t)b * 64 + q) * 512;
#pragma unroll
    for (int ii = 0; ii < 16; ii++) dst[lg + ii * 32] = e[ii] * inv;
    return;
  }
  // ---- MFMA ctx blocks ----
  int b = bid & 7, nt = bid >> 3;
  int n0 = nt * 64;
  int wave = t >> 6, lane = t & 63;
  int mw = (wave >> 1) * 32, nw = (wave & 1) * 32;
  int lr = lane & 31, g = lane >> 5;
  int arow = mw + lr, wrow = nw + lr;
  int lrow = lane >> 3, lblk = lane & 7;
  const _Float16* gAbase =
      Sh + ((size_t)b * 64 + wave * 16 + lrow) * 512 + lblk * 8;
  const _Float16* gWbase =
      keysT + ((size_t)b * 512 + n0 + wave * 16 + lrow) * 512 + lblk * 8;

  floatx16 acc;
#pragma unroll
  for (int i = 0; i < 16; i++) acc[i] = 0.f;

#define STAGE(kt, sel)                                                        \
  {                                                                           \
    int koff = (kt)*64;                                                       \
    GLD16(gAbase + koff, &sA[sel][wave * 16][0]);                             \
    GLD16(gAbase + koff + 8 * 512, &sA[sel][wave * 16 + 8][0]);               \
    GLD16(gWbase + koff, &sW[sel][wave * 16][0]);                             \
    GLD16(gWbase + koff + 8 * 512, &sW[sel][wave * 16 + 8][0]);               \
  }

  STAGE(0, 0);
  for (int kt = 0; kt < 8; kt++) {
    __syncthreads();
    if (kt < 7) STAGE(kt + 1, (kt + 1) & 1);
    int sel = kt & 1;
#pragma unroll
    for (int i = 0; i < 4; i++) {
      int ablk = (((2 * i + g) ^ arow) & 7) * 8 + ((2 * i + g) & ~7) * 8;
      int wblk = (((2 * i + g) ^ wrow) & 7) * 8 + ((2 * i + g) & ~7) * 8;
      half8 af = *reinterpret_cast<const half8*>(&sA[sel][arow][ablk]);
      half8 wf = *reinterpret_cast<const half8*>(&sW[sel][wrow][wblk]);
      acc = __builtin_amdgcn_mfma_f32_32x32x16_f16(af, wf, acc, 0, 0, 0);
    }
  }
#undef STAGE
  int col = n0 + nw + lr;
#pragma unroll
  for (int r = 0; r < 16; r++) {
    int row = mw + (r & 3) + 8 * (r >> 2) + 4 * g;
    ctx[((size_t)b * 64 + row) * 512 + col] = acc[r];
  }
}

// ---------------------------------------------------------------------------
extern "C" void kernel_launch(void* const* d_in, const int* in_sizes, int n_in,
                              void* d_out, int out_size, void* d_ws,
                              size_t ws_size, hipStream_t stream) {
  const float* query = (const float*)d_in[0];
  const float* keys = (const float*)d_in[1];
  const float* Wq = (const float*)d_in[2];
  const float* Wk = (const float*)d_in[3];
  const float* la = (const float*)d_in[4];
  const float* nscalar = (const float*)d_in[5];
  const float* nbias = (const float*)d_in[6];

  float* out = (float*)d_out;
  float* ctx = out;
  float* smx = out + (size_t)B_ * Q_ * D_;

  float* ws = (float*)d_ws;
  float* v = ws + WS_V;
  float* Eq = ws + WS_EQ;
  float* Ek = ws + WS_EK;
  _Float16* Acvt = (_Float16*)(ws + WS_FLOATS);
  _Float16* Wkcvt = Acvt + ACVT_ELEMS;
  _Float16* Wqcvt = Wkcvt + W_ELEMS;
  _Float16* keysT = Wqcvt + W_ELEMS;
  _Float16* Sh = keysT + KT_ELEMS;

  convert_kernel<<<1921, 256, 0, stream>>>(query, keys, Wq, Wk, la, nscalar,
                                           Acvt, Wkcvt, Wqcvt, keysT, v);
  mfma_proj_kernel<<<576, 256, 0, stream>>>(Acvt, Wkcvt, Wqcvt, nbias, Ek, Eq);
  scores_kernel<<<2048, 256, 0, stream>>>(Eq, Ek, v, Sh);
  ctxsm_kernel<<<128, 256, 0, stream>>>(Sh, keysT, ctx, smx);
}